// Round 2
// baseline (455.481 us; speedup 1.0000x reference)
//
#include <hip/hip_runtime.h>
#include <stdint.h>
#include <math.h>

#define B_   4
#define T_   4096
#define BT_  16384
#define HID  2048
#define ED   256
#define HD   32
#define NH   8

typedef unsigned short u16;
typedef __attribute__((ext_vector_type(8))) short short8;
typedef __attribute__((ext_vector_type(4))) float f32x4;

typedef __attribute__((address_space(1))) void gvoid;
typedef __attribute__((address_space(3))) void lvoid;

__device__ __forceinline__ float bf2f(u16 h) {
    return __uint_as_float(((uint32_t)h) << 16);
}
__device__ __forceinline__ u16 f2bf(float f) {
    uint32_t u = __float_as_uint(f);
    u += 0x7FFFu + ((u >> 16) & 1u);   // round-to-nearest-even
    return (u16)(u >> 16);
}

__device__ __forceinline__ void gld_lds16(const void* g, void* l) {
    __builtin_amdgcn_global_load_lds((gvoid*)(uintptr_t)g, (lvoid*)(uintptr_t)l, 16, 0, 0);
}

// ---------------- f32 -> bf16 convert (hi only) ----------------
__global__ void k_cvt(const float* __restrict__ in, u16* __restrict__ out, int n) {
    int i = blockIdx.x * 256 + threadIdx.x;
    if (i < n) out[i] = f2bf(in[i]);
}

// ---------------- f32 -> bf16 split (hi + lo residual) ----------------
__global__ void k_cvt_split(const float* __restrict__ in, u16* __restrict__ hi,
                            u16* __restrict__ lo, int n) {
    int i = blockIdx.x * 256 + threadIdx.x;
    if (i < n) {
        float f = in[i];
        u16 h = f2bf(f);
        hi[i] = h;
        lo[i] = f2bf(f - bf2f(h));
    }
}

// ---------------- hash-embedding gather (f32) ----------------
__global__ void k_gather(const int* __restrict__ hashes, const int* __restrict__ offs,
                         const float* __restrict__ tab, float* __restrict__ E) {
    const int bt = blockIdx.x;
    const int tid = threadIdx.x;          // 256 = 8 heads x 32 dims
    const int head = tid >> 5, d = tid & 31;
    const int row = hashes[bt * NH + head] + offs[head];
    E[(size_t)bt * ED + tid] = tab[(size_t)row * HD + d];
}

// ---- causal dilated depthwise conv + LN + silu + residual (f32, split out) ----
__global__ void k_conv(const float* __restrict__ E, const float* __restrict__ w,
                       const float* __restrict__ lng, const float* __restrict__ lnb,
                       u16* __restrict__ ehi, u16* __restrict__ elo) {
    const int bt = blockIdx.x;
    const int b = bt >> 12;               // T_ = 4096
    const int t = bt & 4095;
    const int ch = threadIdx.x;           // 256
    float c = 0.f;
#pragma unroll
    for (int k = 0; k < 4; ++k) {
        int tt = t - 9 + 3 * k;           // taps at t-9, t-6, t-3, t
        if (tt >= 0)
            c += w[ch * 4 + k] * E[((size_t)(b * T_ + tt)) * ED + ch];
    }
    float s = c, s2 = c * c;
#pragma unroll
    for (int o = 32; o; o >>= 1) { s += __shfl_xor(s, o); s2 += __shfl_xor(s2, o); }
    __shared__ float red[8];
    const int wid = ch >> 6, lane = ch & 63;
    if (!lane) { red[wid] = s; red[4 + wid] = s2; }
    __syncthreads();
    s  = red[0] + red[1] + red[2] + red[3];
    s2 = red[4] + red[5] + red[6] + red[7];
    const float mean = s * (1.f / 256.f);
    const float var  = s2 * (1.f / 256.f) - mean * mean;
    float ln = (c - mean) * rsqrtf(var + 1e-5f) * lng[ch] + lnb[ch];
    float si = ln / (1.f + expf(-ln));    // silu
    float ev = E[(size_t)bt * ED + ch] + si;
    u16 h = f2bf(ev);
    ehi[(size_t)bt * ED + ch] = h;
    elo[(size_t)bt * ED + ch] = f2bf(ev - bf2f(h));
}

// ---------------- per-row: q=LN(x), kln=LN(key f32), g, gamma ----------------
__global__ void k_gamma(const float* __restrict__ x, const float* __restrict__ key,
                        const float* __restrict__ gk, const float* __restrict__ bk,
                        const float* __restrict__ gq, const float* __restrict__ bq,
                        float* __restrict__ gamma) {
    const int m = blockIdx.x;
    const int tid = threadIdx.x;          // 256, 8 elems each
    const float* xr = x + (size_t)m * HID;
    const float* kr = key + (size_t)m * HID;
    float xs[8], ks[8];
    float sx = 0.f, sx2 = 0.f, sk = 0.f, sk2 = 0.f;
#pragma unroll
    for (int i = 0; i < 8; ++i) {
        float xv = xr[tid + i * 256]; xs[i] = xv; sx += xv; sx2 += xv * xv;
        float kv = kr[tid + i * 256]; ks[i] = kv; sk += kv; sk2 += kv * kv;
    }
#pragma unroll
    for (int o = 32; o; o >>= 1) {
        sx += __shfl_xor(sx, o); sx2 += __shfl_xor(sx2, o);
        sk += __shfl_xor(sk, o); sk2 += __shfl_xor(sk2, o);
    }
    __shared__ float red[16];
    const int wid = tid >> 6, lane = tid & 63;
    if (!lane) { red[wid] = sx; red[4 + wid] = sx2; red[8 + wid] = sk; red[12 + wid] = sk2; }
    __syncthreads();
    sx  = red[0] + red[1] + red[2] + red[3];
    sx2 = red[4] + red[5] + red[6] + red[7];
    sk  = red[8] + red[9] + red[10] + red[11];
    sk2 = red[12] + red[13] + red[14] + red[15];
    const float inv = 1.f / (float)HID;
    const float mx = sx * inv, vx = sx2 * inv - mx * mx;
    const float mk = sk * inv, vk = sk2 * inv - mk * mk;
    const float rx = rsqrtf(vx + 1e-5f), rk = rsqrtf(vk + 1e-5f);
    float dot = 0.f;
#pragma unroll
    for (int i = 0; i < 8; ++i) {
        int d = tid + i * 256;
        float q  = (xs[i] - mx) * rx * gq[d] + bq[d];
        float kl = (ks[i] - mk) * rk * gk[d] + bk[d];
        dot += q * kl;
    }
#pragma unroll
    for (int o = 32; o; o >>= 1) dot += __shfl_xor(dot, o);
    __syncthreads();
    if (!lane) red[wid] = dot;
    __syncthreads();
    if (tid == 0) {
        float gd = (red[0] + red[1] + red[2] + red[3]) * 0.022097086912079608f; // 1/sqrt(2048)
        float sg = (gd > 0.f) ? 1.f : ((gd < 0.f) ? -1.f : 0.f);
        float sv = sqrtf(fmaxf(fabsf(gd), 1e-6f)) * sg;
        gamma[m] = 1.f / (1.f + expf(-sv));
    }
}

// ---------------- bf16 MFMA GEMM: C[m,n] = (scale?) * sum_k A[m,k]*B[n,k] ----------------
// A: MxK bf16 row-major, B: NxK bf16 row-major. 128x128 tile, BK=32, 4 waves (2x2 of 64x64).
template <bool SCALE, bool OUTBF16>
__global__ __launch_bounds__(256)
void gemm_bt(const u16* __restrict__ A, const u16* __restrict__ Bm,
             const float* __restrict__ rowscale, void* __restrict__ Cout,
             int M, int N, int K) {
    __shared__ __align__(16) u16 As[128 * 32];
    __shared__ __align__(16) u16 Bs[128 * 32];
    const int tid  = threadIdx.x;
    const int wid  = tid >> 6;
    const int lane = tid & 63;
    const int l15  = lane & 15;
    const int lhi  = lane >> 4;
    const int mblk = blockIdx.x * 128;
    const int nblk = blockIdx.y * 128;
    const int wm = (wid >> 1) * 64;
    const int wn = (wid & 1) * 64;

    f32x4 acc[4][4];
#pragma unroll
    for (int i = 0; i < 4; ++i)
#pragma unroll
        for (int j = 0; j < 4; ++j) acc[i][j] = f32x4{0.f, 0.f, 0.f, 0.f};

    const int o0 = wid * 2048 + lane * 16;
    const int o1 = o0 + 1024;
    const int r0 = o0 >> 6, kc0 = (o0 & 63) >> 1;
    const int r1 = o1 >> 6, kc1 = (o1 & 63) >> 1;
    const u16* Arow0 = A + (size_t)(mblk + r0) * K + kc0;
    const u16* Arow1 = A + (size_t)(mblk + r1) * K + kc1;
    const u16* Brow0 = Bm + (size_t)(nblk + r0) * K + kc0;
    const u16* Brow1 = Bm + (size_t)(nblk + r1) * K + kc1;
    char* AsB0 = (char*)As + wid * 2048;   // wave-uniform LDS bases
    char* AsB1 = AsB0 + 1024;
    char* BsB0 = (char*)Bs + wid * 2048;
    char* BsB1 = BsB0 + 1024;

    const int nk = K >> 5;
    for (int kt = 0; kt < nk; ++kt) {
        const int k0 = kt << 5;
        gld_lds16(Arow0 + k0, AsB0);
        gld_lds16(Arow1 + k0, AsB1);
        gld_lds16(Brow0 + k0, BsB0);
        gld_lds16(Brow1 + k0, BsB1);
        asm volatile("s_waitcnt vmcnt(0)" ::: "memory");
        __syncthreads();
        short8 af[4], bfr[4];
#pragma unroll
        for (int i = 0; i < 4; ++i) {
            af[i]  = *(const short8*)&As[(wm + i * 16 + l15) * 32 + lhi * 8];
            bfr[i] = *(const short8*)&Bs[(wn + i * 16 + l15) * 32 + lhi * 8];
        }
#pragma unroll
        for (int i = 0; i < 4; ++i)
#pragma unroll
            for (int j = 0; j < 4; ++j)
                acc[i][j] = __builtin_amdgcn_mfma_f32_16x16x32_bf16(af[i], bfr[j], acc[i][j], 0, 0, 0);
        __syncthreads();
    }

    // epilogue: D row = (lane>>4)*4 + r, col = lane&15  (m89-verified)
#pragma unroll
    for (int i = 0; i < 4; ++i) {
#pragma unroll
        for (int r = 0; r < 4; ++r) {
            const int m = mblk + wm + i * 16 + lhi * 4 + r;
            const float sc = SCALE ? rowscale[m] : 1.0f;
#pragma unroll
            for (int j = 0; j < 4; ++j) {
                const int n = nblk + wn + j * 16 + l15;
                const float v = acc[i][j][r] * sc;
                if (OUTBF16) ((u16*)Cout)[(size_t)m * N + n] = f2bf(v);
                else         ((float*)Cout)[(size_t)m * N + n] = v;
            }
        }
    }
}

// ------- split-precision MFMA GEMM: C = (Ahi+Alo)(Bhi+Blo)^T, drop lo*lo, f32 out -------
__global__ __launch_bounds__(256)
void gemm_split(const u16* __restrict__ Ahi, const u16* __restrict__ Alo,
                const u16* __restrict__ Bhi, const u16* __restrict__ Blo,
                float* __restrict__ Cout, int M, int N, int K) {
    __shared__ __align__(16) u16 Ash[128 * 32];
    __shared__ __align__(16) u16 Asl[128 * 32];
    __shared__ __align__(16) u16 Bsh[128 * 32];
    __shared__ __align__(16) u16 Bsl[128 * 32];
    const int tid  = threadIdx.x;
    const int wid  = tid >> 6;
    const int lane = tid & 63;
    const int l15  = lane & 15;
    const int lhi  = lane >> 4;
    const int mblk = blockIdx.x * 128;
    const int nblk = blockIdx.y * 128;
    const int wm = (wid >> 1) * 64;
    const int wn = (wid & 1) * 64;

    f32x4 acc[4][4];
#pragma unroll
    for (int i = 0; i < 4; ++i)
#pragma unroll
        for (int j = 0; j < 4; ++j) acc[i][j] = f32x4{0.f, 0.f, 0.f, 0.f};

    const int o0 = wid * 2048 + lane * 16;
    const int o1 = o0 + 1024;
    const int r0 = o0 >> 6, kc0 = (o0 & 63) >> 1;
    const int r1 = o1 >> 6, kc1 = (o1 & 63) >> 1;
    const size_t a0 = (size_t)(mblk + r0) * K + kc0;
    const size_t a1 = (size_t)(mblk + r1) * K + kc1;
    const size_t b0 = (size_t)(nblk + r0) * K + kc0;
    const size_t b1 = (size_t)(nblk + r1) * K + kc1;
    char* AhB0 = (char*)Ash + wid * 2048; char* AhB1 = AhB0 + 1024;
    char* AlB0 = (char*)Asl + wid * 2048; char* AlB1 = AlB0 + 1024;
    char* BhB0 = (char*)Bsh + wid * 2048; char* BhB1 = BhB0 + 1024;
    char* BlB0 = (char*)Bsl + wid * 2048; char* BlB1 = BlB0 + 1024;

    const int nk = K >> 5;
    for (int kt = 0; kt < nk; ++kt) {
        const int k0 = kt << 5;
        gld_lds16(Ahi + a0 + k0, AhB0);
        gld_lds16(Ahi + a1 + k0, AhB1);
        gld_lds16(Alo + a0 + k0, AlB0);
        gld_lds16(Alo + a1 + k0, AlB1);
        gld_lds16(Bhi + b0 + k0, BhB0);
        gld_lds16(Bhi + b1 + k0, BhB1);
        gld_lds16(Blo + b0 + k0, BlB0);
        gld_lds16(Blo + b1 + k0, BlB1);
        asm volatile("s_waitcnt vmcnt(0)" ::: "memory");
        __syncthreads();
        short8 ah[4], al[4], bh[4], bl[4];
#pragma unroll
        for (int i = 0; i < 4; ++i) {
            const int ao = (wm + i * 16 + l15) * 32 + lhi * 8;
            const int bo = (wn + i * 16 + l15) * 32 + lhi * 8;
            ah[i] = *(const short8*)&Ash[ao];
            al[i] = *(const short8*)&Asl[ao];
            bh[i] = *(const short8*)&Bsh[bo];
            bl[i] = *(const short8*)&Bsl[bo];
        }
#pragma unroll
        for (int i = 0; i < 4; ++i)
#pragma unroll
            for (int j = 0; j < 4; ++j) {
                acc[i][j] = __builtin_amdgcn_mfma_f32_16x16x32_bf16(ah[i], bh[j], acc[i][j], 0, 0, 0);
                acc[i][j] = __builtin_amdgcn_mfma_f32_16x16x32_bf16(ah[i], bl[j], acc[i][j], 0, 0, 0);
                acc[i][j] = __builtin_amdgcn_mfma_f32_16x16x32_bf16(al[i], bh[j], acc[i][j], 0, 0, 0);
            }
        __syncthreads();
    }

#pragma unroll
    for (int i = 0; i < 4; ++i)
#pragma unroll
        for (int r = 0; r < 4; ++r) {
            const int m = mblk + wm + i * 16 + lhi * 4 + r;
#pragma unroll
            for (int j = 0; j < 4; ++j) {
                const int n = nblk + wn + j * 16 + l15;
                Cout[(size_t)m * N + n] = acc[i][j][r];
            }
        }
}

extern "C" void kernel_launch(void* const* d_in, const int* in_sizes, int n_in,
                              void* d_out, int out_size, void* d_ws, size_t ws_size,
                              hipStream_t stream) {
    const float* x      = (const float*)d_in[0];
    const int*   hashes = (const int*)d_in[1];
    const int*   offs   = (const int*)d_in[2];
    const float* emb    = (const float*)d_in[3];
    const float* conv_w = (const float*)d_in[4];
    const float* lncg   = (const float*)d_in[5];
    const float* lncb   = (const float*)d_in[6];
    const float* Wk     = (const float*)d_in[7];
    const float* Wv     = (const float*)d_in[8];
    const float* Wo     = (const float*)d_in[9];
    const float* lnkg   = (const float*)d_in[10];
    const float* lnkb   = (const float*)d_in[11];
    const float* lnqg   = (const float*)d_in[12];
    const float* lnqb   = (const float*)d_in[13];

    char* p = (char*)d_ws;
    float* E   = (float*)p; p += (size_t)BT_ * ED * 4;     // 16.8 MB
    u16* ehi   = (u16*)p;   p += (size_t)BT_ * ED * 2;     // 8.39 MB
    u16* elo   = (u16*)p;   p += (size_t)BT_ * ED * 2;     // 8.39 MB
    u16* Wkh   = (u16*)p;   p += (size_t)HID * ED * 2;     // 1 MB
    u16* Wkl   = (u16*)p;   p += (size_t)HID * ED * 2;     // 1 MB
    u16* Wvb   = (u16*)p;   p += (size_t)HID * ED * 2;     // 1 MB
    u16* Wob   = (u16*)p;   p += (size_t)HID * HID * 2;    // 8.39 MB
    float* gamma = (float*)p; p += (size_t)BT_ * 4;        // 64 KB
    float* key = (float*)p; p += (size_t)BT_ * HID * 4;    // 134.2 MB (f32 key; later value bf16)
    u16* value = (u16*)key;                                // aliases key (dead after k_gamma)

    k_cvt_split<<<(HID * ED + 255) / 256, 256, 0, stream>>>(Wk, Wkh, Wkl, HID * ED);
    k_cvt<<<(HID * ED + 255) / 256, 256, 0, stream>>>(Wv, Wvb, HID * ED);
    k_cvt<<<(HID * HID + 255) / 256, 256, 0, stream>>>(Wo, Wob, HID * HID);
    k_gather<<<BT_, 256, 0, stream>>>(hashes, offs, emb, E);
    k_conv<<<BT_, 256, 0, stream>>>(E, conv_w, lncg, lncb, ehi, elo);
    // key = e @ Wk^T in split precision (M=16384, N=2048, K=256) -> f32
    gemm_split<<<dim3(BT_ / 128, HID / 128), 256, 0, stream>>>(ehi, elo, Wkh, Wkl, key, BT_, HID, ED);
    k_gamma<<<BT_, 256, 0, stream>>>(x, key, lnkg, lnkb, lnqg, lnqb, gamma);
    // value = gamma * (e @ Wv^T) -> bf16 (overwrites key region; key is dead)
    gemm_bt<true, true><<<dim3(BT_ / 128, HID / 128), 256, 0, stream>>>(ehi, Wvb, gamma, value, BT_, HID, ED);
    // out = value @ Wo^T  (M=16384, N=2048, K=2048) -> d_out (f32)
    gemm_bt<false, false><<<dim3(BT_ / 128, HID / 128), 256, 0, stream>>>(value, Wob, nullptr, d_out, BT_, HID, HID);
}

// Round 3
// 360.926 us; speedup vs baseline: 1.2620x; 1.2620x over previous
//
#include <hip/hip_runtime.h>
#include <stdint.h>
#include <math.h>

#define B_   4
#define T_   4096
#define BT_  16384
#define HID  2048
#define ED   256
#define HD   32
#define NH   8
#define K3   768   // packed K for split-precision key GEMM

typedef unsigned short u16;
typedef __attribute__((ext_vector_type(8))) short short8;
typedef __attribute__((ext_vector_type(4))) float f32x4;

typedef __attribute__((address_space(1))) void gvoid;
typedef __attribute__((address_space(3))) void lvoid;

__device__ __forceinline__ float bf2f(u16 h) {
    return __uint_as_float(((uint32_t)h) << 16);
}
__device__ __forceinline__ u16 f2bf(float f) {
    uint32_t u = __float_as_uint(f);
    u += 0x7FFFu + ((u >> 16) & 1u);   // round-to-nearest-even
    return (u16)(u >> 16);
}
__device__ __forceinline__ void gld_lds16(const void* g, void* l) {
    __builtin_amdgcn_global_load_lds((gvoid*)(uintptr_t)g, (lvoid*)(uintptr_t)l, 16, 0, 0);
}
__device__ __forceinline__ void BAR() {
    asm volatile("" ::: "memory");
    __builtin_amdgcn_s_barrier();
    asm volatile("" ::: "memory");
}

// ---------------- f32 -> bf16 convert ----------------
__global__ void k_cvt(const float* __restrict__ in, u16* __restrict__ out, int n) {
    int i = blockIdx.x * 256 + threadIdx.x;
    if (i < n) out[i] = f2bf(in[i]);
}

// ---- Wk -> packed [hi | lo | hi] rows of 768 (pairs with A3 = [hi | hi | lo]) ----
__global__ void k_cvt_wk3(const float* __restrict__ in, u16* __restrict__ out) {
    int i = blockIdx.x * 256 + threadIdx.x;   // over HID*ED
    int n = i >> 8, c = i & 255;
    float f = in[i];
    u16 h = f2bf(f);
    out[(size_t)n * K3 + c]       = h;
    out[(size_t)n * K3 + 256 + c] = f2bf(f - bf2f(h));
    out[(size_t)n * K3 + 512 + c] = h;
}

// ---------------- hash-embedding gather (f32) ----------------
__global__ void k_gather(const int* __restrict__ hashes, const int* __restrict__ offs,
                         const float* __restrict__ tab, float* __restrict__ E) {
    const int bt = blockIdx.x;
    const int tid = threadIdx.x;          // 256 = 8 heads x 32 dims
    const int head = tid >> 5, d = tid & 31;
    const int row = hashes[bt * NH + head] + offs[head];
    E[(size_t)bt * ED + tid] = tab[(size_t)row * HD + d];
}

// ---- conv + LN + silu + residual; writes A3 row = [e_hi | e_hi | e_lo] (768) ----
__global__ void k_conv(const float* __restrict__ E, const float* __restrict__ w,
                       const float* __restrict__ lng, const float* __restrict__ lnb,
                       u16* __restrict__ a3) {
    const int bt = blockIdx.x;
    const int b = bt >> 12;               // T_ = 4096
    const int t = bt & 4095;
    const int ch = threadIdx.x;           // 256
    float c = 0.f;
#pragma unroll
    for (int k = 0; k < 4; ++k) {
        int tt = t - 9 + 3 * k;           // taps at t-9, t-6, t-3, t
        if (tt >= 0)
            c += w[ch * 4 + k] * E[((size_t)(b * T_ + tt)) * ED + ch];
    }
    float s = c, s2 = c * c;
#pragma unroll
    for (int o = 32; o; o >>= 1) { s += __shfl_xor(s, o); s2 += __shfl_xor(s2, o); }
    __shared__ float red[8];
    const int wid = ch >> 6, lane = ch & 63;
    if (!lane) { red[wid] = s; red[4 + wid] = s2; }
    __syncthreads();
    s  = red[0] + red[1] + red[2] + red[3];
    s2 = red[4] + red[5] + red[6] + red[7];
    const float mean = s * (1.f / 256.f);
    const float var  = s2 * (1.f / 256.f) - mean * mean;
    float ln = (c - mean) * rsqrtf(var + 1e-5f) * lng[ch] + lnb[ch];
    float si = ln / (1.f + expf(-ln));    // silu
    float ev = E[(size_t)bt * ED + ch] + si;
    u16 h = f2bf(ev);
    a3[(size_t)bt * K3 + ch]       = h;
    a3[(size_t)bt * K3 + 256 + ch] = h;
    a3[(size_t)bt * K3 + 512 + ch] = f2bf(ev - bf2f(h));
}

// ---------------- per-row: q=LN(x), kln=LN(key f32), g, gamma ----------------
__global__ void k_gamma(const float* __restrict__ x, const float* __restrict__ key,
                        const float* __restrict__ gk, const float* __restrict__ bk,
                        const float* __restrict__ gq, const float* __restrict__ bq,
                        float* __restrict__ gamma) {
    const int m = blockIdx.x;
    const int tid = threadIdx.x;          // 256, 8 elems each
    const float* xr = x + (size_t)m * HID;
    const float* kr = key + (size_t)m * HID;
    float xs[8], ks[8];
    float sx = 0.f, sx2 = 0.f, sk = 0.f, sk2 = 0.f;
#pragma unroll
    for (int i = 0; i < 8; ++i) {
        float xv = xr[tid + i * 256]; xs[i] = xv; sx += xv; sx2 += xv * xv;
        float kv = kr[tid + i * 256]; ks[i] = kv; sk += kv; sk2 += kv * kv;
    }
#pragma unroll
    for (int o = 32; o; o >>= 1) {
        sx += __shfl_xor(sx, o); sx2 += __shfl_xor(sx2, o);
        sk += __shfl_xor(sk, o); sk2 += __shfl_xor(sk2, o);
    }
    __shared__ float red[16];
    const int wid = tid >> 6, lane = tid & 63;
    if (!lane) { red[wid] = sx; red[4 + wid] = sx2; red[8 + wid] = sk; red[12 + wid] = sk2; }
    __syncthreads();
    sx  = red[0] + red[1] + red[2] + red[3];
    sx2 = red[4] + red[5] + red[6] + red[7];
    sk  = red[8] + red[9] + red[10] + red[11];
    sk2 = red[12] + red[13] + red[14] + red[15];
    const float inv = 1.f / (float)HID;
    const float mx = sx * inv, vx = sx2 * inv - mx * mx;
    const float mk = sk * inv, vk = sk2 * inv - mk * mk;
    const float rx = rsqrtf(vx + 1e-5f), rk = rsqrtf(vk + 1e-5f);
    float dot = 0.f;
#pragma unroll
    for (int i = 0; i < 8; ++i) {
        int d = tid + i * 256;
        float q  = (xs[i] - mx) * rx * gq[d] + bq[d];
        float kl = (ks[i] - mk) * rk * gk[d] + bk[d];
        dot += q * kl;
    }
#pragma unroll
    for (int o = 32; o; o >>= 1) dot += __shfl_xor(dot, o);
    __syncthreads();
    if (!lane) red[wid] = dot;
    __syncthreads();
    if (tid == 0) {
        float gd = (red[0] + red[1] + red[2] + red[3]) * 0.022097086912079608f; // 1/sqrt(2048)
        float sg = (gd > 0.f) ? 1.f : ((gd < 0.f) ? -1.f : 0.f);
        float sv = sqrtf(fmaxf(fabsf(gd), 1e-6f)) * sg;
        gamma[m] = 1.f / (1.f + expf(-sv));
    }
}

// ================= 256x256 / BK=64 8-phase bf16 MFMA GEMM =================
// C[m,n] = (rowscale[m]?) * sum_k A[m,k]*B[n,k]; A MxK (row stride lda),
// B NxK (row stride ldb), both bf16. 512 thr = 8 waves (2M x 4N), per-wave
// out 128x64. LDS 128 KiB dynamic: A dbuf [0,64K), B dbuf [64K,128K).
// Tile layout per buffer: 256 rows x 128B, XOR-swizzle byte^=((row&7)<<4)
// applied on BOTH stage-source column and ds_read (involution, rule 21).
// Staging: tile t+1 halves at slots (t-1).P4 [A-h0], t.P1 [A-h1], t.P2 [B-h0],
// t.P3 [B-h1]; buffer q=(t+1)&1 is free from (t-1).P3 end-barrier (its last
// ds_read completed before (t-1).P3's MFMA lgkm wait). vmcnt(2) at P4 leaves
// only the P4-issued pair outstanding => all of tile t+1 landed; barrier
// publishes. Never vmcnt(0) in steady state (T4).
template <bool SCALE, bool OUTBF16>
__global__ __launch_bounds__(512, 2)
void gemm8(const u16* __restrict__ A, int lda, const u16* __restrict__ Bm, int ldb,
           const float* __restrict__ rowscale, void* __restrict__ Cout,
           int M, int N, int K) {
    extern __shared__ char smem[];
    const int tid = threadIdx.x, wid = tid >> 6, lane = tid & 63;
    const int l15 = lane & 15, lhi = lane >> 4;
    const int wr = wid >> 2, wc = wid & 3;

    // XCD-aware swizzle (nwg % 8 == 0 here)
    const int tiles_m = M >> 8;
    const int nwg = gridDim.x;
    const int cpx = nwg >> 3;
    const int id = blockIdx.x;
    const int swz = (id & 7) * cpx + (id >> 3);
    const int mblk = (swz % tiles_m) << 8;
    const int nblk = (swz / tiles_m) << 8;

    f32x4 acc[8][4];
#pragma unroll
    for (int i = 0; i < 8; ++i)
#pragma unroll
        for (int j = 0; j < 4; ++j) acc[i][j] = f32x4{0.f, 0.f, 0.f, 0.f};

    // stage source: thread tid stages 16B to linear LDS o = h*16K + r*8K + tid*16
    // row = o>>7, src col pre-swizzled so that LDS[o] = global element at swz(o)
    const int srow = tid >> 3;
    const int scol = ((tid & 7) << 3) ^ ((srow & 7) << 3);
    const u16* aS[4];
    const u16* bS[4];
#pragma unroll
    for (int h = 0; h < 2; ++h)
#pragma unroll
        for (int r = 0; r < 2; ++r) {
            aS[h * 2 + r] = A  + (size_t)(mblk + h * 128 + r * 64 + srow) * lda + scol;
            bS[h * 2 + r] = Bm + (size_t)(nblk + h * 128 + r * 64 + srow) * ldb + scol;
        }
    const int wb = wid * 1024;   // wave-uniform byte base within half-round

    const int koff0 = (lhi * 16) ^ ((l15 & 7) << 4);
    const int koff1 = (64 + lhi * 16) ^ ((l15 & 7) << 4);

    short8 ar[4][2], br[2][2][2];

#define STAGE_A(h, tt) do { const int q_ = (tt) & 1; const int kk_ = (tt) << 6;      \
        char* d_ = smem + q_ * 32768 + (h) * 16384 + wb;                             \
        gld_lds16(aS[(h) * 2 + 0] + kk_, d_);                                        \
        gld_lds16(aS[(h) * 2 + 1] + kk_, d_ + 8192); } while (0)
#define STAGE_B(h, tt) do { const int q_ = (tt) & 1; const int kk_ = (tt) << 6;      \
        char* d_ = smem + 65536 + q_ * 32768 + (h) * 16384 + wb;                     \
        gld_lds16(bS[(h) * 2 + 0] + kk_, d_);                                        \
        gld_lds16(bS[(h) * 2 + 1] + kk_, d_ + 8192); } while (0)
#define LDA_SUB(mh, p) do {                                                          \
        const char* ab_ = smem + (p) * 32768 + (wr * 128 + (mh) * 64) * 128;         \
        _Pragma("unroll") for (int fm = 0; fm < 4; ++fm) {                           \
            const char* rb_ = ab_ + (fm * 16 + l15) * 128;                           \
            ar[fm][0] = *(const short8*)(rb_ + koff0);                               \
            ar[fm][1] = *(const short8*)(rb_ + koff1); } } while (0)
#define LDB_SUB(nh, p) do {                                                          \
        const char* bb_ = smem + 65536 + (p) * 32768 + (wc * 64 + (nh) * 32) * 128;  \
        _Pragma("unroll") for (int fn = 0; fn < 2; ++fn) {                           \
            const char* rb_ = bb_ + (fn * 16 + l15) * 128;                           \
            br[nh][fn][0] = *(const short8*)(rb_ + koff0);                           \
            br[nh][fn][1] = *(const short8*)(rb_ + koff1); } } while (0)
#define MMQ(mh, nh) do { __builtin_amdgcn_s_setprio(1);                              \
        _Pragma("unroll") for (int fm = 0; fm < 4; ++fm)                             \
        _Pragma("unroll") for (int fn = 0; fn < 2; ++fn) {                           \
            acc[(mh) * 4 + fm][(nh) * 2 + fn] = __builtin_amdgcn_mfma_f32_16x16x32_bf16( \
                ar[fm][0], br[nh][fn][0], acc[(mh) * 4 + fm][(nh) * 2 + fn], 0, 0, 0);   \
            acc[(mh) * 4 + fm][(nh) * 2 + fn] = __builtin_amdgcn_mfma_f32_16x16x32_bf16( \
                ar[fm][1], br[nh][fn][1], acc[(mh) * 4 + fm][(nh) * 2 + fn], 0, 0, 0); } \
        __builtin_amdgcn_s_setprio(0); } while (0)

    // prologue: tile0 fully + tile1 A-h0 (10 items); wait oldest 8 (tile0)
    STAGE_A(0, 0); STAGE_A(1, 0); STAGE_B(0, 0); STAGE_B(1, 0);
    STAGE_A(0, 1);
    asm volatile("s_waitcnt vmcnt(2)" ::: "memory");
    BAR();

    const int nk = K >> 6;
    for (int t = 0; t < nk; ++t) {
        const int p = t & 1;
        const bool st1 = (t + 1 < nk);
        // P1: A(mh0)+B(nh0) [12 ds_read] ; stage A-h1(t+1)
        LDA_SUB(0, p); LDB_SUB(0, p);
        if (st1) STAGE_A(1, t + 1);
        BAR(); MMQ(0, 0); BAR();
        // P2: B(nh1) ; stage B-h0(t+1)
        LDB_SUB(1, p);
        if (st1) STAGE_B(0, t + 1);
        BAR(); MMQ(0, 1); BAR();
        // P3: A(mh1) ; stage B-h1(t+1)   (last reads of buffer p)
        LDA_SUB(1, p);
        if (st1) STAGE_B(1, t + 1);
        BAR(); MMQ(1, 1); BAR();
        // P4: stage A-h0(t+2) into buffer p (freed by P3 end-barrier); counted wait
        if (t + 2 < nk) {
            STAGE_A(0, t + 2);
            asm volatile("s_waitcnt vmcnt(2)" ::: "memory");
        } else {
            asm volatile("s_waitcnt vmcnt(0)" ::: "memory");
        }
        BAR(); MMQ(1, 0); BAR();
    }
#undef STAGE_A
#undef STAGE_B
#undef LDA_SUB
#undef LDB_SUB
#undef MMQ

    // epilogue: D row=(lane>>4)*4+r, col=lane&15 per 16x16 fragment
#pragma unroll
    for (int mi = 0; mi < 8; ++mi) {
#pragma unroll
        for (int rr = 0; rr < 4; ++rr) {
            const int m = mblk + wr * 128 + mi * 16 + lhi * 4 + rr;
            const float sc = SCALE ? rowscale[m] : 1.0f;
#pragma unroll
            for (int nj = 0; nj < 4; ++nj) {
                const int n = nblk + wc * 64 + nj * 16 + l15;
                const float v = acc[mi][nj][rr] * sc;
                if (OUTBF16) ((u16*)Cout)[(size_t)m * N + n] = f2bf(v);
                else         ((float*)Cout)[(size_t)m * N + n] = v;
            }
        }
    }
}

extern "C" void kernel_launch(void* const* d_in, const int* in_sizes, int n_in,
                              void* d_out, int out_size, void* d_ws, size_t ws_size,
                              hipStream_t stream) {
    const float* x      = (const float*)d_in[0];
    const int*   hashes = (const int*)d_in[1];
    const int*   offs   = (const int*)d_in[2];
    const float* emb    = (const float*)d_in[3];
    const float* conv_w = (const float*)d_in[4];
    const float* lncg   = (const float*)d_in[5];
    const float* lncb   = (const float*)d_in[6];
    const float* Wk     = (const float*)d_in[7];
    const float* Wv     = (const float*)d_in[8];
    const float* Wo     = (const float*)d_in[9];
    const float* lnkg   = (const float*)d_in[10];
    const float* lnkb   = (const float*)d_in[11];
    const float* lnqg   = (const float*)d_in[12];
    const float* lnqb   = (const float*)d_in[13];

    // ws layout: E (16.8MB) and value (67MB) alias the key region (134MB);
    // lifetimes: E ends at k_conv; key written by GEMM1, dead after k_gamma;
    // value written by GEMM2. Total ws = 172 MB.
    char* p = (char*)d_ws;
    float* key   = (float*)p;
    float* E     = (float*)p;
    u16*   value = (u16*)p;  p += (size_t)BT_ * HID * 4;
    u16*   A3    = (u16*)p;  p += (size_t)BT_ * K3 * 2;
    u16*   Wk3   = (u16*)p;  p += (size_t)HID * K3 * 2;
    u16*   Wvb   = (u16*)p;  p += (size_t)HID * ED * 2;
    u16*   Wob   = (u16*)p;  p += (size_t)HID * HID * 2;
    float* gamma = (float*)p; p += (size_t)BT_ * 4;

    hipFuncSetAttribute((const void*)gemm8<false, false>,
                        hipFuncAttributeMaxDynamicSharedMemorySize, 131072);
    hipFuncSetAttribute((const void*)gemm8<true, true>,
                        hipFuncAttributeMaxDynamicSharedMemorySize, 131072);

    k_cvt<<<(HID * ED + 255) / 256, 256, 0, stream>>>(Wv, Wvb, HID * ED);
    k_cvt<<<(HID * HID + 255) / 256, 256, 0, stream>>>(Wo, Wob, HID * HID);
    k_cvt_wk3<<<(HID * ED) / 256, 256, 0, stream>>>(Wk, Wk3);
    k_gather<<<BT_, 256, 0, stream>>>(hashes, offs, emb, E);
    k_conv<<<BT_, 256, 0, stream>>>(E, conv_w, lncg, lncb, A3);
    // key = [ehi|ehi|elo] @ [Wkhi|Wklo|Wkhi]^T  (K'=768) -> f32
    gemm8<false, false><<<dim3((BT_ / 256) * (HID / 256)), 512, 131072, stream>>>(
        A3, K3, Wk3, K3, nullptr, key, BT_, HID, K3);
    k_gamma<<<BT_, 256, 0, stream>>>(x, key, lnkg, lnkb, lnqg, lnqb, gamma);
    // value = gamma * (ehi @ Wv^T)  (K=256) -> bf16 (overwrites dead key)
    gemm8<true, true><<<dim3((BT_ / 256) * (HID / 256)), 512, 131072, stream>>>(
        A3, K3, Wvb, ED, gamma, value, BT_, HID, ED);
    // out = value @ Wo^T  (K=2048) -> f32
    gemm8<false, false><<<dim3((BT_ / 256) * (HID / 256)), 512, 131072, stream>>>(
        value, HID, Wob, HID, nullptr, d_out, BT_, HID, HID);
}